// Round 1
// baseline (217.992 us; speedup 1.0000x reference)
//
#include <hip/hip_runtime.h>
#include <math.h>

#define NPTS 2048
#define BLOCK 256
#define BPB 4                        // batch elements per block (one per wave)
#define CHUNKS (NPTS / (64 * 4))     // 8 chunks; each lane: 4 points/chunk

// One WAVE per batch element (4 waves/block, grid = B/4 blocks, fully
// resident at 4 waves/SIMD). Each lane streams 32 points via a 1-deep
// prefetch pipeline (12 float4 loads in flight), accumulates the 17
// Kabsch sufficient statistics, wave-butterfly-reduces once per 2048
// points, and lane 0 runs the closed-form 3x3 eigen epilogue in double.
// The 4 per-wave RMSDs combine in LDS -> one atomicAdd per block.
__global__ __launch_bounds__(BLOCK, 4) void kabsch_kernel(
    const float* __restrict__ P, const float* __restrict__ C,
    float* __restrict__ out, int B) {
  const int wave = threadIdx.x >> 6;
  const int lane = threadIdx.x & 63;
  const int b = blockIdx.x * BPB + wave;

  double rmsd = 0.0;
  if (b < B) {
    const float4* p4 = (const float4*)(P + (size_t)b * (NPTS * 3));
    const float4* c4 = (const float4*)(C + (size_t)b * (NPTS * 3));

    // 0-2 sum(p), 3-5 sum(c), 6 sum|p|^2, 7 sum|c|^2, 8-16 sum p_j*c_k
    float acc[17];
#pragma unroll
    for (int i = 0; i < 17; i++) acc[i] = 0.f;

    int base = 3 * lane;  // float4 index; stride 192 float4 per chunk
    float4 pa = p4[base], pb = p4[base + 1], pq = p4[base + 2];
    float4 ca = c4[base], cb = c4[base + 1], cq = c4[base + 2];
#pragma unroll
    for (int k = 0; k < CHUNKS; k++) {
      float4 npa, npb, npq, nca, ncb, ncq;
      if (k + 1 < CHUNKS) {  // prefetch next chunk before consuming current
        const int nb = base + 64 * 3;
        npa = p4[nb]; npb = p4[nb + 1]; npq = p4[nb + 2];
        nca = c4[nb]; ncb = c4[nb + 1]; ncq = c4[nb + 2];
        base = nb;
      }
      // de-interleave 12 floats -> 4 points (x,y,z)
      const float Px[4] = {pa.x, pa.w, pb.z, pq.y};
      const float Py[4] = {pa.y, pb.x, pb.w, pq.z};
      const float Pz[4] = {pa.z, pb.y, pq.x, pq.w};
      const float Cx[4] = {ca.x, ca.w, cb.z, cq.y};
      const float Cy[4] = {ca.y, cb.x, cb.w, cq.z};
      const float Cz[4] = {ca.z, cb.y, cq.x, cq.w};
#pragma unroll
      for (int i = 0; i < 4; i++) {
        const float px = Px[i], py = Py[i], pz = Pz[i];
        const float cx = Cx[i], cy = Cy[i], cz = Cz[i];
        acc[0] += px; acc[1] += py; acc[2] += pz;
        acc[3] += cx; acc[4] += cy; acc[5] += cz;
        acc[6] += px * px + py * py + pz * pz;
        acc[7] += cx * cx + cy * cy + cz * cz;
        acc[8]  += px * cx; acc[9]  += px * cy; acc[10] += px * cz;
        acc[11] += py * cx; acc[12] += py * cy; acc[13] += py * cz;
        acc[14] += pz * cx; acc[15] += pz * cy; acc[16] += pz * cz;
      }
      pa = npa; pb = npb; pq = npq;
      ca = nca; cb = ncb; cq = ncq;
    }

    // wave (64-lane) butterfly reduce; lane 0 ends with the full sums
#pragma unroll
    for (int off = 32; off > 0; off >>= 1) {
#pragma unroll
      for (int i = 0; i < 17; i++) acc[i] += __shfl_down(acc[i], off);
    }

    if (lane == 0) {
      double s[17];
#pragma unroll
      for (int i = 0; i < 17; i++) s[i] = (double)acc[i];
      const double invN = 1.0 / (double)NPTS;
      const double spx = s[0], spy = s[1], spz = s[2];
      const double scx = s[3], scy = s[4], scz = s[5];
      const double Ep = s[6] - (spx * spx + spy * spy + spz * spz) * invN;
      const double Ec = s[7] - (scx * scx + scy * scy + scz * scz) * invN;
      // centered cross-covariance A (3x3)
      const double a00 = s[8]  - spx * scx * invN, a01 = s[9]  - spx * scy * invN, a02 = s[10] - spx * scz * invN;
      const double a10 = s[11] - spy * scx * invN, a11 = s[12] - spy * scy * invN, a12 = s[13] - spy * scz * invN;
      const double a20 = s[14] - spz * scx * invN, a21 = s[15] - spz * scy * invN, a22 = s[16] - spz * scz * invN;
      const double det = a00 * (a11 * a22 - a12 * a21)
                       - a01 * (a10 * a22 - a12 * a20)
                       + a02 * (a10 * a21 - a11 * a20);
      // Gram matrix G = A^T A (symmetric PSD); singular values = sqrt(eig(G))
      const double b00 = a00 * a00 + a10 * a10 + a20 * a20;
      const double b11 = a01 * a01 + a11 * a11 + a21 * a21;
      const double b22 = a02 * a02 + a12 * a12 + a22 * a22;
      const double b01 = a00 * a01 + a10 * a11 + a20 * a21;
      const double b02 = a00 * a02 + a10 * a12 + a20 * a22;
      const double b12 = a01 * a02 + a11 * a12 + a21 * a22;
      const double q = (b00 + b11 + b22) / 3.0;
      const double p1 = b01 * b01 + b02 * b02 + b12 * b12;
      const double d0 = b00 - q, d1 = b11 - q, d2 = b22 - q;
      const double p2 = d0 * d0 + d1 * d1 + d2 * d2 + 2.0 * p1;
      double e1, e2, e3;
      if (p2 < 1e-30) {
        e1 = e2 = e3 = q;
      } else {
        const double pp = sqrt(p2 / 6.0);
        const double inv = 1.0 / pp;
        const double c00 = d0 * inv, c11 = d1 * inv, c22 = d2 * inv;
        const double c01 = b01 * inv, c02 = b02 * inv, c12 = b12 * inv;
        double r = 0.5 * (c00 * (c11 * c22 - c12 * c12)
                        - c01 * (c01 * c22 - c12 * c02)
                        + c02 * (c01 * c12 - c11 * c02));
        r = fmin(1.0, fmax(-1.0, r));
        const double phi = acos(r) / 3.0;
        e1 = q + 2.0 * pp * cos(phi);
        e3 = q + 2.0 * pp * cos(phi + 2.0943951023931953);  // smallest
        e2 = 3.0 * q - e1 - e3;
      }
      const double s1 = sqrt(fmax(e1, 0.0));
      const double s2 = sqrt(fmax(e2, 0.0));
      const double s3 = sqrt(fmax(e3, 0.0));
      const double dsign = (det > 0.0) ? 1.0 : ((det < 0.0) ? -1.0 : 0.0);
      const double trRS = s1 + s2 + dsign * s3;  // tr(R A^T)
      const double msd = (Ep + Ec - 2.0 * trRS) * invN;
      rmsd = sqrt(fmax(msd, 0.0));
    }
  }

  // combine the 4 per-wave RMSDs -> one atomic per block
  __shared__ double red[BPB];
  if (lane == 0) red[wave] = rmsd;
  __syncthreads();
  if (threadIdx.x == 0) {
    const double sum = red[0] + red[1] + red[2] + red[3];
    atomicAdd(out, (float)(sum / (double)B));
  }
}

extern "C" void kernel_launch(void* const* d_in, const int* in_sizes, int n_in,
                              void* d_out, int out_size, void* d_ws, size_t ws_size,
                              hipStream_t stream) {
  const float* P = (const float*)d_in[0];
  const float* C = (const float*)d_in[1];
  float* out = (float*)d_out;
  const int B = in_sizes[0] / (NPTS * 3);
  hipMemsetAsync(out, 0, sizeof(float), stream);  // d_out poisoned before every call
  kabsch_kernel<<<(B + BPB - 1) / BPB, BLOCK, 0, stream>>>(P, C, out, B);
}

// Round 2
// 217.195 us; speedup vs baseline: 1.0037x; 1.0037x over previous
//
#include <hip/hip_runtime.h>
#include <math.h>

#define NPTS 2048
#define BLOCK 256
#define BPB 4                        // batch elements per block (one per wave)
#define CHUNKS (NPTS / (64 * 4))     // 8 chunks; each lane: 4 points/chunk

// One WAVE per batch element (4 waves/block, grid = B/4 blocks).
// Each lane streams 32 points with a software-pipelined 1-deep prefetch:
// the next chunk's 12 float4 loads are issued and PINNED above the current
// chunk's accumulate via sched_barrier(0), so ~12 KB/wave stays in flight
// instead of one serialized round-trip per chunk (the round-1 compile at
// 40 VGPRs proved the compiler sinks these loads unless pinned).
__global__ __launch_bounds__(BLOCK, 4) void kabsch_kernel(
    const float* __restrict__ P, const float* __restrict__ C,
    float* __restrict__ out, int B) {
  const int wave = threadIdx.x >> 6;
  const int lane = threadIdx.x & 63;
  const int b = blockIdx.x * BPB + wave;

  double rmsd = 0.0;
  if (b < B) {
    const float4* p4 = (const float4*)(P + (size_t)b * (NPTS * 3));
    const float4* c4 = (const float4*)(C + (size_t)b * (NPTS * 3));

    // 0-2 sum(p), 3-5 sum(c), 6 sum|p|^2, 7 sum|c|^2, 8-16 sum p_j*c_k
    float acc[17];
#pragma unroll
    for (int i = 0; i < 17; i++) acc[i] = 0.f;

#define ACCUM(PA, PB, PQ, CA, CB, CQ)                                   \
  do {                                                                  \
    const float Px[4] = {PA.x, PA.w, PB.z, PQ.y};                       \
    const float Py[4] = {PA.y, PB.x, PB.w, PQ.z};                       \
    const float Pz[4] = {PA.z, PB.y, PQ.x, PQ.w};                       \
    const float Cx[4] = {CA.x, CA.w, CB.z, CQ.y};                       \
    const float Cy[4] = {CA.y, CB.x, CB.w, CQ.z};                       \
    const float Cz[4] = {CA.z, CB.y, CQ.x, CQ.w};                       \
    _Pragma("unroll")                                                   \
    for (int i = 0; i < 4; i++) {                                       \
      const float px = Px[i], py = Py[i], pz = Pz[i];                   \
      const float cx = Cx[i], cy = Cy[i], cz = Cz[i];                   \
      acc[0] += px; acc[1] += py; acc[2] += pz;                         \
      acc[3] += cx; acc[4] += cy; acc[5] += cz;                         \
      acc[6] += px * px + py * py + pz * pz;                            \
      acc[7] += cx * cx + cy * cy + cz * cz;                            \
      acc[8]  += px * cx; acc[9]  += px * cy; acc[10] += px * cz;       \
      acc[11] += py * cx; acc[12] += py * cy; acc[13] += py * cz;       \
      acc[14] += pz * cx; acc[15] += pz * cy; acc[16] += pz * cz;       \
    }                                                                   \
  } while (0)

    int base = 3 * lane;  // float4 index; chunk stride = 192 float4 (3 KB)
    float4 pa = p4[base], pb = p4[base + 1], pq = p4[base + 2];
    float4 ca = c4[base], cb = c4[base + 1], cq = c4[base + 2];
#pragma unroll
    for (int k = 0; k < CHUNKS - 1; k++) {
      base += 64 * 3;
      // prefetch next chunk (12 independent dwordx4 loads)
      const float4 npa = p4[base], npb = p4[base + 1], npq = p4[base + 2];
      const float4 nca = c4[base], ncb = c4[base + 1], ncq = c4[base + 2];
      // pin: loads above may not sink below; math below may not hoist above
      __builtin_amdgcn_sched_barrier(0);
      ACCUM(pa, pb, pq, ca, cb, cq);
      pa = npa; pb = npb; pq = npq;
      ca = nca; cb = ncb; cq = ncq;
    }
    ACCUM(pa, pb, pq, ca, cb, cq);  // peeled last chunk

    // wave (64-lane) butterfly reduce; lane 0 ends with the full sums
#pragma unroll
    for (int off = 32; off > 0; off >>= 1) {
#pragma unroll
      for (int i = 0; i < 17; i++) acc[i] += __shfl_down(acc[i], off);
    }

    if (lane == 0) {
      double s[17];
#pragma unroll
      for (int i = 0; i < 17; i++) s[i] = (double)acc[i];
      const double invN = 1.0 / (double)NPTS;
      const double spx = s[0], spy = s[1], spz = s[2];
      const double scx = s[3], scy = s[4], scz = s[5];
      const double Ep = s[6] - (spx * spx + spy * spy + spz * spz) * invN;
      const double Ec = s[7] - (scx * scx + scy * scy + scz * scz) * invN;
      // centered cross-covariance A (3x3)
      const double a00 = s[8]  - spx * scx * invN, a01 = s[9]  - spx * scy * invN, a02 = s[10] - spx * scz * invN;
      const double a10 = s[11] - spy * scx * invN, a11 = s[12] - spy * scy * invN, a12 = s[13] - spy * scz * invN;
      const double a20 = s[14] - spz * scx * invN, a21 = s[15] - spz * scy * invN, a22 = s[16] - spz * scz * invN;
      const double det = a00 * (a11 * a22 - a12 * a21)
                       - a01 * (a10 * a22 - a12 * a20)
                       + a02 * (a10 * a21 - a11 * a20);
      // Gram matrix G = A^T A (symmetric PSD); singular values = sqrt(eig(G))
      const double b00 = a00 * a00 + a10 * a10 + a20 * a20;
      const double b11 = a01 * a01 + a11 * a11 + a21 * a21;
      const double b22 = a02 * a02 + a12 * a12 + a22 * a22;
      const double b01 = a00 * a01 + a10 * a11 + a20 * a21;
      const double b02 = a00 * a02 + a10 * a12 + a20 * a22;
      const double b12 = a01 * a02 + a11 * a12 + a21 * a22;
      const double q = (b00 + b11 + b22) / 3.0;
      const double p1 = b01 * b01 + b02 * b02 + b12 * b12;
      const double d0 = b00 - q, d1 = b11 - q, d2 = b22 - q;
      const double p2 = d0 * d0 + d1 * d1 + d2 * d2 + 2.0 * p1;
      double e1, e2, e3;
      if (p2 < 1e-30) {
        e1 = e2 = e3 = q;
      } else {
        const double pp = sqrt(p2 / 6.0);
        const double inv = 1.0 / pp;
        const double c00 = d0 * inv, c11 = d1 * inv, c22 = d2 * inv;
        const double c01 = b01 * inv, c02 = b02 * inv, c12 = b12 * inv;
        double r = 0.5 * (c00 * (c11 * c22 - c12 * c12)
                        - c01 * (c01 * c22 - c12 * c02)
                        + c02 * (c01 * c12 - c11 * c02));
        r = fmin(1.0, fmax(-1.0, r));
        const double phi = acos(r) / 3.0;
        e1 = q + 2.0 * pp * cos(phi);
        e3 = q + 2.0 * pp * cos(phi + 2.0943951023931953);  // smallest
        e2 = 3.0 * q - e1 - e3;
      }
      const double s1 = sqrt(fmax(e1, 0.0));
      const double s2 = sqrt(fmax(e2, 0.0));
      const double s3 = sqrt(fmax(e3, 0.0));
      const double dsign = (det > 0.0) ? 1.0 : ((det < 0.0) ? -1.0 : 0.0);
      const double trRS = s1 + s2 + dsign * s3;  // tr(R A^T)
      const double msd = (Ep + Ec - 2.0 * trRS) * invN;
      rmsd = sqrt(fmax(msd, 0.0));
    }
  }

  // combine the 4 per-wave RMSDs -> one atomic per block
  __shared__ double red[BPB];
  if (lane == 0) red[wave] = rmsd;
  __syncthreads();
  if (threadIdx.x == 0) {
    const double sum = red[0] + red[1] + red[2] + red[3];
    atomicAdd(out, (float)(sum / (double)B));
  }
}

extern "C" void kernel_launch(void* const* d_in, const int* in_sizes, int n_in,
                              void* d_out, int out_size, void* d_ws, size_t ws_size,
                              hipStream_t stream) {
  const float* P = (const float*)d_in[0];
  const float* C = (const float*)d_in[1];
  float* out = (float*)d_out;
  const int B = in_sizes[0] / (NPTS * 3);
  hipMemsetAsync(out, 0, sizeof(float), stream);  // d_out poisoned before every call
  kabsch_kernel<<<(B + BPB - 1) / BPB, BLOCK, 0, stream>>>(P, C, out, B);
}